// Round 1
// baseline (766.538 us; speedup 1.0000x reference)
//
#include <hip/hip_runtime.h>

typedef unsigned short u16;
typedef unsigned int u32;
typedef __bf16 bf16x8 __attribute__((ext_vector_type(8)));
typedef float f32x4 __attribute__((ext_vector_type(4)));

#define DM 1024
#define B_ 8
#define T_ 2048
#define NN 32768
#define NH 16
#define DH 64
#define KF 64

__device__ __forceinline__ u16 f2bf(float f) {
  u32 x = __float_as_uint(f);
  x = (x + 0x7fffu + ((x >> 16) & 1u)) >> 16;
  return (u16)x;
}
__device__ __forceinline__ u32 mono(float f) {
  u32 x = __float_as_uint(f);
  return (x & 0x80000000u) ? ~x : (x | 0x80000000u);
}

// ---------------- zero-init accumulators + full_attn region ----------------
__global__ void k_zero(float* __restrict__ fullattn, float* __restrict__ colsum,
                       float* __restrict__ mattn) {
  int i = blockIdx.x * 256 + threadIdx.x;   // grid = 1024 blocks -> 262144 exactly
  fullattn[i] = 0.f;
  if (i < B_ * DM) colsum[i] = 0.f;
  if (i < B_ * KF) mattn[i] = 0.f;
}

// ---------------- transpose 4 weights f32(K x N) -> bf16(N x K) ----------------
__global__ __launch_bounds__(256) void k_transpose(
    const float* __restrict__ w0, const float* __restrict__ w1,
    const float* __restrict__ w2, const float* __restrict__ w3,
    u16* __restrict__ o0, u16* __restrict__ o1, u16* __restrict__ o2, u16* __restrict__ o3) {
  __shared__ float t[32][33];
  const float* w = blockIdx.z == 0 ? w0 : blockIdx.z == 1 ? w1 : blockIdx.z == 2 ? w2 : w3;
  u16* o = blockIdx.z == 0 ? o0 : blockIdx.z == 1 ? o1 : blockIdx.z == 2 ? o2 : o3;
  int tx = threadIdx.x & 31, ty = threadIdx.x >> 5;
  int kb = blockIdx.y * 32, nb = blockIdx.x * 32;
#pragma unroll
  for (int j = 0; j < 32; j += 8) t[ty + j][tx] = w[(size_t)(kb + ty + j) * DM + nb + tx];
  __syncthreads();
#pragma unroll
  for (int j = 0; j < 32; j += 8) o[(size_t)(nb + ty + j) * DM + kb + tx] = f2bf(t[tx][ty + j]);
}

// ---------------- LayerNorm: h f32 -> h_norm bf16 + (mu,rstd) per row ----------------
__global__ __launch_bounds__(256) void k_ln(const float* __restrict__ h, const float* __restrict__ g,
                                            const float* __restrict__ be, u16* __restrict__ hn,
                                            float* __restrict__ murstd) {
  int r = blockIdx.x, tid = threadIdx.x;
  float4 v = *(const float4*)(h + (size_t)r * DM + tid * 4);
  float s = v.x + v.y + v.z + v.w;
  float q = v.x * v.x + v.y * v.y + v.z * v.z + v.w * v.w;
#pragma unroll
  for (int off = 1; off < 64; off <<= 1) {
    s += __shfl_xor(s, off, 64);
    q += __shfl_xor(q, off, 64);
  }
  __shared__ float rs[4], rq[4];
  int w = tid >> 6;
  if ((tid & 63) == 0) { rs[w] = s; rq[w] = q; }
  __syncthreads();
  s = rs[0] + rs[1] + rs[2] + rs[3];
  q = rq[0] + rq[1] + rq[2] + rq[3];
  float mu = s * (1.f / 1024.f);
  float rstd = rsqrtf(q * (1.f / 1024.f) - mu * mu + 1e-5f);
  float4 gg = *(const float4*)(g + tid * 4);
  float4 bb = *(const float4*)(be + tid * 4);
  float n0 = (v.x - mu) * rstd * gg.x + bb.x;
  float n1 = (v.y - mu) * rstd * gg.y + bb.y;
  float n2 = (v.z - mu) * rstd * gg.z + bb.z;
  float n3 = (v.w - mu) * rstd * gg.w + bb.w;
  uint2 o;
  o.x = (u32)f2bf(n0) | ((u32)f2bf(n1) << 16);
  o.y = (u32)f2bf(n2) | ((u32)f2bf(n3) << 16);
  *(uint2*)(hn + (size_t)r * DM + tid * 4) = o;
  if (tid == 0) { murstd[r * 2] = mu; murstd[r * 2 + 1] = rstd; }
}

// ---------------- column sums of (h-mu)*rstd (fp32, for h_summary) ----------------
__global__ __launch_bounds__(256) void k_summary(const float* __restrict__ h,
                                                 const float* __restrict__ murstd,
                                                 float* __restrict__ colsum) {
  int col = blockIdx.x * 256 + threadIdx.x;
  int b = blockIdx.z;
  int tb = blockIdx.y * 128;
  float acc = 0.f;
  for (int t = 0; t < 128; ++t) {
    int r = b * T_ + tb + t;
    float mu = murstd[r * 2], rsd = murstd[r * 2 + 1];
    acc += (h[(size_t)r * DM + col] - mu) * rsd;
  }
  atomicAdd(&colsum[b * DM + col], acc);
}

// ---------------- focus_query = h_summary @ focus_w + focus_b (fp32) ----------------
__global__ __launch_bounds__(256) void k_focus(const float* __restrict__ colsum,
                                               const float* __restrict__ lng, const float* __restrict__ lnb,
                                               const float* __restrict__ fw, const float* __restrict__ fb,
                                               float* __restrict__ fq) {
  int gid = blockIdx.x * 256 + threadIdx.x;
  int b = gid >> 10, dout = gid & 1023;
  float acc = fb[dout];
  for (int i = 0; i < DM; ++i) {
    float hs = lng[i] * (colsum[b * DM + i] * (1.f / 2048.f)) + lnb[i];
    acc += hs * fw[(size_t)i * DM + dout];
  }
  fq[gid] = acc;
}

// ---------------- selection[b][n] = fq[b]·memory[n] + aw*act[b][n] (fp32) ----------------
__global__ __launch_bounds__(256) void k_selection(const float* __restrict__ mem,
                                                   const float* __restrict__ fqg,
                                                   const float* __restrict__ act,
                                                   const float* __restrict__ awp,
                                                   float* __restrict__ sel) {
  __shared__ float fqs[8][1024];
  int tid = threadIdx.x;
#pragma unroll
  for (int i = 0; i < 8; ++i) {
    int e = i * 256 + tid;
    ((float4*)&fqs[0][0])[e] = ((const float4*)fqg)[e];
  }
  __syncthreads();
  float aw = awp[0];
  int l = tid & 63, w = tid >> 6;
  for (int n = blockIdx.x * 4 + w; n < NN; n += gridDim.x * 4) {
    const float* mrow = mem + (size_t)n * DM;
    float accb[8] = {0, 0, 0, 0, 0, 0, 0, 0};
#pragma unroll
    for (int c = 0; c < 4; ++c) {
      int d = c * 256 + l * 4;
      float4 mv = *(const float4*)(mrow + d);
#pragma unroll
      for (int b2 = 0; b2 < 8; ++b2) {
        float4 fv = *(const float4*)&fqs[b2][d];
        accb[b2] += mv.x * fv.x + mv.y * fv.y + mv.z * fv.z + mv.w * fv.w;
      }
    }
#pragma unroll
    for (int off = 1; off < 64; off <<= 1) {
#pragma unroll
      for (int b2 = 0; b2 < 8; ++b2) accb[b2] += __shfl_xor(accb[b2], off, 64);
    }
    if (l < 8) {
      float vsel = accb[0];
#pragma unroll
      for (int j = 1; j < 8; ++j) vsel = (l == j) ? accb[j] : vsel;
      sel[(size_t)l * NN + n] = vsel + aw * act[(size_t)l * NN + n];
    }
  }
}

// ---------------- exact top-64 per batch via 2-level radix histogram ----------------
#define CAND 1024
__global__ __launch_bounds__(1024) void k_topk(const float* __restrict__ sel, int* __restrict__ idx) {
  int b = blockIdx.x, tid = threadIdx.x;
  __shared__ u32 hist[256], hist2[256];
  __shared__ int scb, sA, ssb, sA2, nDef, nCand;
  __shared__ u32 cu[CAND];
  __shared__ int cn[CAND];
  __shared__ unsigned long long amax;
  if (tid < 256) { hist[tid] = 0; hist2[tid] = 0; }
  if (tid == 0) { nDef = 0; nCand = 0; }
  __syncthreads();
  const float* row = sel + (size_t)b * NN;
  for (int i = tid; i < NN; i += 1024) atomicAdd(&hist[mono(row[i]) >> 24], 1u);
  __syncthreads();
  if (tid < 256) {
    u32 s = 0;
    for (int j = tid + 1; j < 256; ++j) s += hist[j];
    if ((int)s < KF && (int)(s + hist[tid]) >= KF) { scb = tid; sA = (int)s; }
  }
  __syncthreads();
  int cb = scb;
  int R = KF - sA;
  for (int i = tid; i < NN; i += 1024) {
    u32 u = mono(row[i]);
    if ((int)(u >> 24) == cb) atomicAdd(&hist2[(u >> 16) & 255], 1u);
  }
  __syncthreads();
  if (tid < 256) {
    u32 s = 0;
    for (int j = tid + 1; j < 256; ++j) s += hist2[j];
    if ((int)s < R && (int)(s + hist2[tid]) >= R) { ssb = tid; sA2 = (int)s; }
  }
  __syncthreads();
  int R2 = R - sA2;
  u32 T16 = ((u32)cb << 8) | (u32)ssb;
  for (int i = tid; i < NN; i += 1024) {
    u32 u = mono(row[i]);
    u32 t = u >> 16;
    if (t > T16) {
      int p = atomicAdd(&nDef, 1);
      idx[b * KF + p] = i;
    } else if (t == T16) {
      int p = atomicAdd(&nCand, 1);
      if (p < CAND) { cu[p] = u; cn[p] = i; }
    }
  }
  __syncthreads();
  int base = nDef;
  int nc = nCand < CAND ? nCand : CAND;
  for (int r = 0; r < R2; ++r) {
    if (tid == 0) amax = 0;
    __syncthreads();
    unsigned long long loc = 0;
    for (int i = tid; i < nc; i += 1024) {
      unsigned long long key = ((unsigned long long)cu[i] << 32) | (u32)i;
      if (key > loc) loc = key;
    }
    if (loc) atomicMax(&amax, loc);
    __syncthreads();
    if (tid == 0) {
      int pos = (int)(amax & 0xffffffffu);
      idx[b * KF + base + r] = cn[pos];
      cu[pos] = 0;
    }
    __syncthreads();
  }
}

// ---------------- gather topk memory rows -> bf16 ----------------
__global__ __launch_bounds__(256) void k_gather(const float* __restrict__ mem,
                                                const int* __restrict__ idx, u16* __restrict__ tm) {
  int rowi = blockIdx.x;
  int n = idx[rowi];
  float4 v = ((const float4*)(mem + (size_t)n * DM))[threadIdx.x];
  uint2 o;
  o.x = (u32)f2bf(v.x) | ((u32)f2bf(v.y) << 16);
  o.y = (u32)f2bf(v.z) | ((u32)f2bf(v.w) << 16);
  *(uint2*)(tm + (size_t)rowi * DM + threadIdx.x * 4) = o;
}

// ---------------- bf16 MFMA GEMM: C = A(MxK) * Bt(NxK)^T + bias, flexible epilogue ----
// mode 0: out bf16 row-major (q)       mode 1: out f32 = h + gate*(acc+bias)
// mode 2: out bf16 k_ws [b][h][ks][dh] mode 3: out bf16 vT_ws [b][h][dh][ks]
__global__ __launch_bounds__(256) void k_gemm(const u16* __restrict__ A, const u16* __restrict__ Bt,
                                              const float* __restrict__ bias, void* __restrict__ out,
                                              const float* __restrict__ hsrc, const float* __restrict__ gatep,
                                              int M, int N, int K, int mode) {
  __shared__ u16 As[128][40];
  __shared__ u16 Bs[128][40];
  int tid = threadIdx.x;
  int l = tid & 63, w = tid >> 6;
  int l15 = l & 15, quad = l >> 4;
  int wm = w >> 1, wn = w & 1;
  int m0 = blockIdx.y * 128, n0 = blockIdx.x * 128;
  int srow = tid >> 1, sseg = (tid & 1) * 16;
  const u16* ga = A + (size_t)(m0 + srow) * K + sseg;
  const u16* gb = Bt + (size_t)(n0 + srow) * K + sseg;
  f32x4 zero = {0.f, 0.f, 0.f, 0.f};
  f32x4 acc[4][4];
#pragma unroll
  for (int mt = 0; mt < 4; ++mt)
#pragma unroll
    for (int nt = 0; nt < 4; ++nt) acc[mt][nt] = zero;
  for (int kt = 0; kt < K; kt += 32) {
    uint4 a0 = *(const uint4*)(ga + kt);
    uint4 a1 = *(const uint4*)(ga + kt + 8);
    uint4 b0 = *(const uint4*)(gb + kt);
    uint4 b1 = *(const uint4*)(gb + kt + 8);
    __syncthreads();
    *(uint4*)&As[srow][sseg] = a0;
    *(uint4*)&As[srow][sseg + 8] = a1;
    *(uint4*)&Bs[srow][sseg] = b0;
    *(uint4*)&Bs[srow][sseg + 8] = b1;
    __syncthreads();
    bf16x8 af[4], bfr[4];
#pragma unroll
    for (int t = 0; t < 4; ++t) {
      af[t] = *(const bf16x8*)&As[wm * 64 + t * 16 + l15][quad * 8];
      bfr[t] = *(const bf16x8*)&Bs[wn * 64 + t * 16 + l15][quad * 8];
    }
#pragma unroll
    for (int mt = 0; mt < 4; ++mt)
#pragma unroll
      for (int nt = 0; nt < 4; ++nt)
        acc[mt][nt] = __builtin_amdgcn_mfma_f32_16x16x32_bf16(af[mt], bfr[nt], acc[mt][nt], 0, 0, 0);
  }
  float gv = 0.f;
  if (mode == 1) gv = 1.f / (1.f + __expf(-gatep[0]));
#pragma unroll
  for (int mt = 0; mt < 4; ++mt) {
#pragma unroll
    for (int nt = 0; nt < 4; ++nt) {
      int col = n0 + wn * 64 + nt * 16 + l15;
      float bv = bias[col];
#pragma unroll
      for (int reg = 0; reg < 4; ++reg) {
        int rrow = m0 + wm * 64 + mt * 16 + quad * 4 + reg;
        float v = acc[mt][nt][reg] + bv;
        if (mode == 0) {
          ((u16*)out)[(size_t)rrow * N + col] = f2bf(v);
        } else if (mode == 1) {
          size_t o = (size_t)rrow * N + col;
          ((float*)out)[o] = hsrc[o] + gv * v;
        } else {
          int bb = rrow >> 6, ks = rrow & 63, hh = col >> 6, dh = col & 63;
          size_t o;
          if (mode == 2) o = ((((size_t)bb * NH + hh) * KF + ks) * DH + dh);
          else o = ((((size_t)bb * NH + hh) * DH + dh) * KF + ks);
          ((u16*)out)[o] = f2bf(v);
        }
      }
    }
  }
}

// ---------------- fused small-K attention: S=QK^T/8, softmax, O=PV ----------------
__global__ __launch_bounds__(256) void k_attn(const u16* __restrict__ q, const u16* __restrict__ kk,
                                              const u16* __restrict__ vt, u16* __restrict__ o,
                                              float* __restrict__ mattn) {
  __shared__ u16 Qs[128][72];
  __shared__ u16 Ps[128][72];
  __shared__ u16 Ks[64][72];
  __shared__ u16 Vs[64][72];
  int tid = threadIdx.x;
  int t0 = blockIdx.x * 128, hh = blockIdx.y, b = blockIdx.z;
  {
    int row = tid >> 1, seg = tid & 1;
    const uint4* src = (const uint4*)(q + ((size_t)(b * T_ + t0 + row)) * DM + hh * DH + seg * 32);
#pragma unroll
    for (int j = 0; j < 4; ++j) *(uint4*)&Qs[row][seg * 32 + j * 8] = src[j];
  }
  {
    int row = tid >> 2, seg = tid & 3;
    size_t base = (((size_t)b * NH + hh) * 64 + row) * 64 + seg * 16;
    const uint4* sk = (const uint4*)(kk + base);
    const uint4* sv = (const uint4*)(vt + base);
    *(uint4*)&Ks[row][seg * 16] = sk[0];
    *(uint4*)&Ks[row][seg * 16 + 8] = sk[1];
    *(uint4*)&Vs[row][seg * 16] = sv[0];
    *(uint4*)&Vs[row][seg * 16 + 8] = sv[1];
  }
  __syncthreads();
  int l = tid & 63, w = tid >> 6;
  int l15 = l & 15, quad = l >> 4;
  f32x4 zero = {0.f, 0.f, 0.f, 0.f};
  f32x4 sacc[2][4];
#pragma unroll
  for (int mt = 0; mt < 2; ++mt)
#pragma unroll
    for (int nt = 0; nt < 4; ++nt) sacc[mt][nt] = zero;
#pragma unroll
  for (int step = 0; step < 2; ++step) {
    bf16x8 aq0 = *(const bf16x8*)&Qs[w * 32 + l15][step * 32 + quad * 8];
    bf16x8 aq1 = *(const bf16x8*)&Qs[w * 32 + 16 + l15][step * 32 + quad * 8];
#pragma unroll
    for (int nt = 0; nt < 4; ++nt) {
      bf16x8 bk = *(const bf16x8*)&Ks[nt * 16 + l15][step * 32 + quad * 8];
      sacc[0][nt] = __builtin_amdgcn_mfma_f32_16x16x32_bf16(aq0, bk, sacc[0][nt], 0, 0, 0);
      sacc[1][nt] = __builtin_amdgcn_mfma_f32_16x16x32_bf16(aq1, bk, sacc[1][nt], 0, 0, 0);
    }
  }
  float csum[4] = {0, 0, 0, 0};
#pragma unroll
  for (int mt = 0; mt < 2; ++mt) {
#pragma unroll
    for (int reg = 0; reg < 4; ++reg) {
      float s0 = sacc[mt][0][reg] * 0.125f;
      float s1 = sacc[mt][1][reg] * 0.125f;
      float s2 = sacc[mt][2][reg] * 0.125f;
      float s3 = sacc[mt][3][reg] * 0.125f;
      float mx = fmaxf(fmaxf(s0, s1), fmaxf(s2, s3));
#pragma unroll
      for (int off = 1; off < 16; off <<= 1) mx = fmaxf(mx, __shfl_xor(mx, off, 64));
      float p0 = __expf(s0 - mx), p1 = __expf(s1 - mx), p2 = __expf(s2 - mx), p3 = __expf(s3 - mx);
      float sum = p0 + p1 + p2 + p3;
#pragma unroll
      for (int off = 1; off < 16; off <<= 1) sum += __shfl_xor(sum, off, 64);
      float inv = 1.f / sum;
      p0 *= inv; p1 *= inv; p2 *= inv; p3 *= inv;
      int row = w * 32 + mt * 16 + quad * 4 + reg;
      Ps[row][0 * 16 + l15] = f2bf(p0);
      Ps[row][1 * 16 + l15] = f2bf(p1);
      Ps[row][2 * 16 + l15] = f2bf(p2);
      Ps[row][3 * 16 + l15] = f2bf(p3);
      csum[0] += p0; csum[1] += p1; csum[2] += p2; csum[3] += p3;
    }
  }
#pragma unroll
  for (int nt = 0; nt < 4; ++nt) {
    float v = csum[nt];
    v += __shfl_xor(v, 16, 64);
    v += __shfl_xor(v, 32, 64);
    if (quad == 0) atomicAdd(&mattn[b * KF + nt * 16 + l15], v);
  }
  __syncthreads();
  f32x4 oacc[2][4];
#pragma unroll
  for (int mt = 0; mt < 2; ++mt)
#pragma unroll
    for (int nt = 0; nt < 4; ++nt) oacc[mt][nt] = zero;
#pragma unroll
  for (int step = 0; step < 2; ++step) {
    bf16x8 ap0 = *(const bf16x8*)&Ps[w * 32 + l15][step * 32 + quad * 8];
    bf16x8 ap1 = *(const bf16x8*)&Ps[w * 32 + 16 + l15][step * 32 + quad * 8];
#pragma unroll
    for (int nt = 0; nt < 4; ++nt) {
      bf16x8 bv = *(const bf16x8*)&Vs[nt * 16 + l15][step * 32 + quad * 8];
      oacc[0][nt] = __builtin_amdgcn_mfma_f32_16x16x32_bf16(ap0, bv, oacc[0][nt], 0, 0, 0);
      oacc[1][nt] = __builtin_amdgcn_mfma_f32_16x16x32_bf16(ap1, bv, oacc[1][nt], 0, 0, 0);
    }
  }
#pragma unroll
  for (int mt = 0; mt < 2; ++mt)
#pragma unroll
    for (int nt = 0; nt < 4; ++nt)
#pragma unroll
      for (int reg = 0; reg < 4; ++reg) {
        int row = t0 + w * 32 + mt * 16 + quad * 4 + reg;
        int col = hh * DH + nt * 16 + l15;
        o[((size_t)(b * T_ + row)) * DM + col] = f2bf(oacc[mt][nt][reg]);
      }
}

// ---------------- scatter mean attention ----------------
__global__ void k_scatter(const float* __restrict__ mattn, const int* __restrict__ tidx,
                          float* __restrict__ out_attn) {
  int i = threadIdx.x;  // 512 threads
  int b = i >> 6;
  out_attn[(size_t)b * NN + tidx[i]] = mattn[i] * (1.f / 32768.f);
}

extern "C" void kernel_launch(void* const* d_in, const int* in_sizes, int n_in,
                              void* d_out, int out_size, void* d_ws, size_t ws_size,
                              hipStream_t stream) {
  const float* h = (const float*)d_in[0];
  const float* mem = (const float*)d_in[1];
  const float* act = (const float*)d_in[2];
  const float* lng = (const float*)d_in[3];
  const float* lnb = (const float*)d_in[4];
  const float* fw = (const float*)d_in[5];
  const float* fb = (const float*)d_in[6];
  const float* qw = (const float*)d_in[7];
  const float* qb = (const float*)d_in[8];
  const float* kw = (const float*)d_in[9];
  const float* kb = (const float*)d_in[10];
  const float* vw = (const float*)d_in[11];
  const float* vb = (const float*)d_in[12];
  const float* ow = (const float*)d_in[13];
  const float* ob = (const float*)d_in[14];
  const float* awp = (const float*)d_in[15];
  const float* glp = (const float*)d_in[16];
  float* out_h = (float*)d_out;
  float* out_attn = out_h + (size_t)B_ * T_ * DM;

  char* p = (char*)d_ws;
  size_t off = 0;
  auto take = [&](size_t bytes) {
    void* r = p + off;
    off += (bytes + 255) & ~(size_t)255;
    return r;
  };
  u16* hnorm = (u16*)take((size_t)B_ * T_ * DM * 2);  // reused as O after GEMM1
  u16* q_ws = (u16*)take((size_t)B_ * T_ * DM * 2);
  u16* qwT = (u16*)take((size_t)DM * DM * 2);
  u16* kwT = (u16*)take((size_t)DM * DM * 2);
  u16* vwT = (u16*)take((size_t)DM * DM * 2);
  u16* owT = (u16*)take((size_t)DM * DM * 2);
  float* selw = (float*)take((size_t)B_ * NN * 4);
  u16* tmem = (u16*)take((size_t)B_ * KF * DM * 2);
  u16* k_ws = (u16*)take((size_t)B_ * NH * KF * DH * 2);
  u16* vT_ws = (u16*)take((size_t)B_ * NH * KF * DH * 2);
  float* murstd = (float*)take((size_t)B_ * T_ * 2 * 4);
  float* colsum = (float*)take((size_t)B_ * DM * 4);
  float* fq = (float*)take((size_t)B_ * DM * 4);
  float* mattn = (float*)take((size_t)B_ * KF * 4);
  int* tidx = (int*)take((size_t)B_ * KF * 4);
  u16* o_ws = hnorm;

  k_zero<<<1024, 256, 0, stream>>>(out_attn, colsum, mattn);
  k_transpose<<<dim3(32, 32, 4), 256, 0, stream>>>(qw, kw, vw, ow, qwT, kwT, vwT, owT);
  k_ln<<<B_ * T_, 256, 0, stream>>>(h, lng, lnb, hnorm, murstd);
  k_gemm<<<dim3(8, 128), 256, 0, stream>>>(hnorm, qwT, qb, q_ws, nullptr, nullptr, B_ * T_, DM, DM, 0);
  k_summary<<<dim3(4, 16, 8), 256, 0, stream>>>(h, murstd, colsum);
  k_focus<<<32, 256, 0, stream>>>(colsum, lng, lnb, fw, fb, fq);
  k_selection<<<2048, 256, 0, stream>>>(mem, fq, act, awp, selw);
  k_topk<<<8, 1024, 0, stream>>>(selw, tidx);
  k_gather<<<B_ * KF, 256, 0, stream>>>(mem, tidx, tmem);
  k_gemm<<<dim3(8, 4), 256, 0, stream>>>(tmem, kwT, kb, k_ws, nullptr, nullptr, B_ * KF, DM, DM, 2);
  k_gemm<<<dim3(8, 4), 256, 0, stream>>>(tmem, vwT, vb, vT_ws, nullptr, nullptr, B_ * KF, DM, DM, 3);
  k_attn<<<dim3(16, 16, 8), 256, 0, stream>>>(q_ws, k_ws, vT_ws, o_ws, mattn);
  k_gemm<<<dim3(8, 128), 256, 0, stream>>>(o_ws, owT, ob, out_h, h, glp, B_ * T_, DM, DM, 1);
  k_scatter<<<1, 512, 0, stream>>>(mattn, tidx, out_attn);
}

// Round 2
// 734.966 us; speedup vs baseline: 1.0430x; 1.0430x over previous
//
#include <hip/hip_runtime.h>

typedef unsigned short u16;
typedef unsigned int u32;
typedef __bf16 bf16x8 __attribute__((ext_vector_type(8)));
typedef float f32x4 __attribute__((ext_vector_type(4)));

#define DM 1024
#define B_ 8
#define T_ 2048
#define NN 32768
#define NH 16
#define DH 64
#define KF 64

__device__ __forceinline__ u16 f2bf(float f) {
  u32 x = __float_as_uint(f);
  x = (x + 0x7fffu + ((x >> 16) & 1u)) >> 16;
  return (u16)x;
}
__device__ __forceinline__ u32 mono(float f) {
  u32 x = __float_as_uint(f);
  return (x & 0x80000000u) ? ~x : (x | 0x80000000u);
}
// async global->LDS, 16B per lane; LDS dest is wave-uniform base + lane*16
__device__ __forceinline__ void async16(const void* g, void* s) {
  __builtin_amdgcn_global_load_lds((const __attribute__((address_space(1))) void*)g,
                                   (__attribute__((address_space(3))) void*)s, 16, 0, 0);
}

// ---------------- zero-init accumulators + full_attn region ----------------
__global__ void k_zero(float* __restrict__ fullattn, float* __restrict__ colsum,
                       float* __restrict__ mattn) {
  int i = blockIdx.x * 256 + threadIdx.x;   // grid = 1024 blocks -> 262144 exactly
  fullattn[i] = 0.f;
  if (i < B_ * DM) colsum[i] = 0.f;
  if (i < B_ * KF) mattn[i] = 0.f;
}

// ---------------- transpose 4 weights f32(K x N) -> bf16(N x K) ----------------
__global__ __launch_bounds__(256) void k_transpose(
    const float* __restrict__ w0, const float* __restrict__ w1,
    const float* __restrict__ w2, const float* __restrict__ w3,
    u16* __restrict__ o0, u16* __restrict__ o1, u16* __restrict__ o2, u16* __restrict__ o3) {
  __shared__ float t[32][33];
  const float* w = blockIdx.z == 0 ? w0 : blockIdx.z == 1 ? w1 : blockIdx.z == 2 ? w2 : w3;
  u16* o = blockIdx.z == 0 ? o0 : blockIdx.z == 1 ? o1 : blockIdx.z == 2 ? o2 : o3;
  int tx = threadIdx.x & 31, ty = threadIdx.x >> 5;
  int kb = blockIdx.y * 32, nb = blockIdx.x * 32;
#pragma unroll
  for (int j = 0; j < 32; j += 8) t[ty + j][tx] = w[(size_t)(kb + ty + j) * DM + nb + tx];
  __syncthreads();
#pragma unroll
  for (int j = 0; j < 32; j += 8) o[(size_t)(nb + ty + j) * DM + kb + tx] = f2bf(t[tx][ty + j]);
}

// ---------------- LayerNorm: h f32 -> h_norm bf16 + (mu,rstd) per row ----------------
__global__ __launch_bounds__(256) void k_ln(const float* __restrict__ h, const float* __restrict__ g,
                                            const float* __restrict__ be, u16* __restrict__ hn,
                                            float* __restrict__ murstd) {
  int r = blockIdx.x, tid = threadIdx.x;
  float4 v = *(const float4*)(h + (size_t)r * DM + tid * 4);
  float s = v.x + v.y + v.z + v.w;
  float q = v.x * v.x + v.y * v.y + v.z * v.z + v.w * v.w;
#pragma unroll
  for (int off = 1; off < 64; off <<= 1) {
    s += __shfl_xor(s, off, 64);
    q += __shfl_xor(q, off, 64);
  }
  __shared__ float rs[4], rq[4];
  int w = tid >> 6;
  if ((tid & 63) == 0) { rs[w] = s; rq[w] = q; }
  __syncthreads();
  s = rs[0] + rs[1] + rs[2] + rs[3];
  q = rq[0] + rq[1] + rq[2] + rq[3];
  float mu = s * (1.f / 1024.f);
  float rstd = rsqrtf(q * (1.f / 1024.f) - mu * mu + 1e-5f);
  float4 gg = *(const float4*)(g + tid * 4);
  float4 bb = *(const float4*)(be + tid * 4);
  float n0 = (v.x - mu) * rstd * gg.x + bb.x;
  float n1 = (v.y - mu) * rstd * gg.y + bb.y;
  float n2 = (v.z - mu) * rstd * gg.z + bb.z;
  float n3 = (v.w - mu) * rstd * gg.w + bb.w;
  uint2 o;
  o.x = (u32)f2bf(n0) | ((u32)f2bf(n1) << 16);
  o.y = (u32)f2bf(n2) | ((u32)f2bf(n3) << 16);
  *(uint2*)(hn + (size_t)r * DM + tid * 4) = o;
  if (tid == 0) { murstd[r * 2] = mu; murstd[r * 2 + 1] = rstd; }
}

// ---------------- column sums of (h-mu)*rstd (fp32, for h_summary) ----------------
__global__ __launch_bounds__(256) void k_summary(const float* __restrict__ h,
                                                 const float* __restrict__ murstd,
                                                 float* __restrict__ colsum) {
  int col = blockIdx.x * 256 + threadIdx.x;
  int b = blockIdx.z;
  int tb = blockIdx.y * 128;
  float acc = 0.f;
  for (int t = 0; t < 128; ++t) {
    int r = b * T_ + tb + t;
    float mu = murstd[r * 2], rsd = murstd[r * 2 + 1];
    acc += (h[(size_t)r * DM + col] - mu) * rsd;
  }
  atomicAdd(&colsum[b * DM + col], acc);
}

// ---------------- focus_query = h_summary @ focus_w + focus_b (fp32) ----------------
__global__ __launch_bounds__(256) void k_focus(const float* __restrict__ colsum,
                                               const float* __restrict__ lng, const float* __restrict__ lnb,
                                               const float* __restrict__ fw, const float* __restrict__ fb,
                                               float* __restrict__ fq) {
  int gid = blockIdx.x * 256 + threadIdx.x;
  int b = gid >> 10, dout = gid & 1023;
  float acc = fb[dout];
  for (int i = 0; i < DM; ++i) {
    float hs = lng[i] * (colsum[b * DM + i] * (1.f / 2048.f)) + lnb[i];
    acc += hs * fw[(size_t)i * DM + dout];
  }
  fq[gid] = acc;
}

// ---------------- selection[b][n] = fq[b]·memory[n] + aw*act[b][n] (fp32) ----------------
__global__ __launch_bounds__(256) void k_selection(const float* __restrict__ mem,
                                                   const float* __restrict__ fqg,
                                                   const float* __restrict__ act,
                                                   const float* __restrict__ awp,
                                                   float* __restrict__ sel) {
  __shared__ float fqs[8][1024];
  int tid = threadIdx.x;
#pragma unroll
  for (int i = 0; i < 8; ++i) {
    int e = i * 256 + tid;
    ((float4*)&fqs[0][0])[e] = ((const float4*)fqg)[e];
  }
  __syncthreads();
  float aw = awp[0];
  int l = tid & 63, w = tid >> 6;
  for (int n = blockIdx.x * 4 + w; n < NN; n += gridDim.x * 4) {
    const float* mrow = mem + (size_t)n * DM;
    float accb[8] = {0, 0, 0, 0, 0, 0, 0, 0};
#pragma unroll
    for (int c = 0; c < 4; ++c) {
      int d = c * 256 + l * 4;
      float4 mv = *(const float4*)(mrow + d);
#pragma unroll
      for (int b2 = 0; b2 < 8; ++b2) {
        float4 fv = *(const float4*)&fqs[b2][d];
        accb[b2] += mv.x * fv.x + mv.y * fv.y + mv.z * fv.z + mv.w * fv.w;
      }
    }
#pragma unroll
    for (int off = 1; off < 64; off <<= 1) {
#pragma unroll
      for (int b2 = 0; b2 < 8; ++b2) accb[b2] += __shfl_xor(accb[b2], off, 64);
    }
    if (l < 8) {
      float vsel = accb[0];
#pragma unroll
      for (int j = 1; j < 8; ++j) vsel = (l == j) ? accb[j] : vsel;
      sel[(size_t)l * NN + n] = vsel + aw * act[(size_t)l * NN + n];
    }
  }
}

// ---------------- exact top-64 per batch via 2-level radix histogram ----------------
#define CAND 1024
__global__ __launch_bounds__(1024) void k_topk(const float* __restrict__ sel, int* __restrict__ idx) {
  int b = blockIdx.x, tid = threadIdx.x;
  __shared__ u32 hist[256], hist2[256];
  __shared__ int scb, sA, ssb, sA2, nDef, nCand;
  __shared__ u32 cu[CAND];
  __shared__ int cn[CAND];
  __shared__ unsigned long long amax;
  if (tid < 256) { hist[tid] = 0; hist2[tid] = 0; }
  if (tid == 0) { nDef = 0; nCand = 0; }
  __syncthreads();
  const float* row = sel + (size_t)b * NN;
  for (int i = tid; i < NN; i += 1024) atomicAdd(&hist[mono(row[i]) >> 24], 1u);
  __syncthreads();
  if (tid < 256) {
    u32 s = 0;
    for (int j = tid + 1; j < 256; ++j) s += hist[j];
    if ((int)s < KF && (int)(s + hist[tid]) >= KF) { scb = tid; sA = (int)s; }
  }
  __syncthreads();
  int cb = scb;
  int R = KF - sA;
  for (int i = tid; i < NN; i += 1024) {
    u32 u = mono(row[i]);
    if ((int)(u >> 24) == cb) atomicAdd(&hist2[(u >> 16) & 255], 1u);
  }
  __syncthreads();
  if (tid < 256) {
    u32 s = 0;
    for (int j = tid + 1; j < 256; ++j) s += hist2[j];
    if ((int)s < R && (int)(s + hist2[tid]) >= R) { ssb = tid; sA2 = (int)s; }
  }
  __syncthreads();
  int R2 = R - sA2;
  u32 T16 = ((u32)cb << 8) | (u32)ssb;
  for (int i = tid; i < NN; i += 1024) {
    u32 u = mono(row[i]);
    u32 t = u >> 16;
    if (t > T16) {
      int p = atomicAdd(&nDef, 1);
      idx[b * KF + p] = i;
    } else if (t == T16) {
      int p = atomicAdd(&nCand, 1);
      if (p < CAND) { cu[p] = u; cn[p] = i; }
    }
  }
  __syncthreads();
  int base = nDef;
  int nc = nCand < CAND ? nCand : CAND;
  for (int r = 0; r < R2; ++r) {
    if (tid == 0) amax = 0;
    __syncthreads();
    unsigned long long loc = 0;
    for (int i = tid; i < nc; i += 1024) {
      unsigned long long key = ((unsigned long long)cu[i] << 32) | (u32)i;
      if (key > loc) loc = key;
    }
    if (loc) atomicMax(&amax, loc);
    __syncthreads();
    if (tid == 0) {
      int pos = (int)(amax & 0xffffffffu);
      idx[b * KF + base + r] = cn[pos];
      cu[pos] = 0;
    }
    __syncthreads();
  }
}

// ---------------- gather topk memory rows -> bf16 ----------------
__global__ __launch_bounds__(256) void k_gather(const float* __restrict__ mem,
                                                const int* __restrict__ idx, u16* __restrict__ tm) {
  int rowi = blockIdx.x;
  int n = idx[rowi];
  float4 v = ((const float4*)(mem + (size_t)n * DM))[threadIdx.x];
  uint2 o;
  o.x = (u32)f2bf(v.x) | ((u32)f2bf(v.y) << 16);
  o.y = (u32)f2bf(v.z) | ((u32)f2bf(v.w) << 16);
  *(uint2*)(tm + (size_t)rowi * DM + threadIdx.x * 4) = o;
}

// ---------------- bf16 MFMA GEMM: C = A(MxK) * Bt(NxK)^T + bias, flexible epilogue ----
// grid: x = m-tiles (so blocks sharing an A-tile land on the same XCD: flat ids
//       differ by gridDim.x = multiple of 8), y = n-tiles.
// Staging: global_load_lds width=16, unpadded LDS (wave-uniform base + lane*16).
// mode 0: out bf16 row-major (q)       mode 1: out f32 = h + gate*(acc+bias)
// mode 2: out bf16 k_ws [b][h][ks][dh] mode 3: out bf16 vT_ws [b][h][dh][ks]
__global__ __launch_bounds__(256) void k_gemm(const u16* __restrict__ A, const u16* __restrict__ Bt,
                                              const float* __restrict__ bias, void* __restrict__ out,
                                              const float* __restrict__ hsrc, const float* __restrict__ gatep,
                                              int M, int N, int K, int mode) {
  __shared__ __align__(16) u16 As[128 * 32];
  __shared__ __align__(16) u16 Bs[128 * 32];
  int tid = threadIdx.x;
  int l = tid & 63, w = tid >> 6;
  int l15 = l & 15, quad = l >> 4;
  int wm = w >> 1, wn = w & 1;
  int m0 = blockIdx.x * 128, n0 = blockIdx.y * 128;
  // staging addresses: wave w, lane i covers row w*16 + (i>>2), k-seg (i&3)*8 (16B)
  int srow = w * 16 + (l >> 2);
  int koff = (l & 3) * 8;
  const u16* ga = A + (size_t)(m0 + srow) * K + koff;
  const u16* gb = Bt + (size_t)(n0 + srow) * K + koff;
  u16* lA0 = &As[(w * 16) * 32];
  u16* lA1 = &As[(64 + w * 16) * 32];
  u16* lB0 = &Bs[(w * 16) * 32];
  u16* lB1 = &Bs[(64 + w * 16) * 32];
  size_t rstride = (size_t)64 * K;
  f32x4 zero = {0.f, 0.f, 0.f, 0.f};
  f32x4 acc[4][4];
#pragma unroll
  for (int mt = 0; mt < 4; ++mt)
#pragma unroll
    for (int nt = 0; nt < 4; ++nt) acc[mt][nt] = zero;
  for (int kt = 0; kt < K; kt += 32) {
    __syncthreads();  // previous iteration's LDS reads done
    async16(ga + kt, lA0);
    async16(ga + rstride + kt, lA1);
    async16(gb + kt, lB0);
    async16(gb + rstride + kt, lB1);
    __syncthreads();  // loads landed (vmcnt drained before barrier)
    bf16x8 af[4], bfr[4];
#pragma unroll
    for (int t = 0; t < 4; ++t) {
      af[t] = *(const bf16x8*)&As[(wm * 64 + t * 16 + l15) * 32 + quad * 8];
      bfr[t] = *(const bf16x8*)&Bs[(wn * 64 + t * 16 + l15) * 32 + quad * 8];
    }
#pragma unroll
    for (int mt = 0; mt < 4; ++mt)
#pragma unroll
      for (int nt = 0; nt < 4; ++nt)
        acc[mt][nt] = __builtin_amdgcn_mfma_f32_16x16x32_bf16(af[mt], bfr[nt], acc[mt][nt], 0, 0, 0);
  }
  float gv = 0.f;
  if (mode == 1) gv = 1.f / (1.f + __expf(-gatep[0]));
#pragma unroll
  for (int mt = 0; mt < 4; ++mt) {
#pragma unroll
    for (int nt = 0; nt < 4; ++nt) {
      int col = n0 + wn * 64 + nt * 16 + l15;
      float bv = bias[col];
#pragma unroll
      for (int reg = 0; reg < 4; ++reg) {
        int rrow = m0 + wm * 64 + mt * 16 + quad * 4 + reg;
        float v = acc[mt][nt][reg] + bv;
        if (mode == 0) {
          ((u16*)out)[(size_t)rrow * N + col] = f2bf(v);
        } else if (mode == 1) {
          size_t o = (size_t)rrow * N + col;
          ((float*)out)[o] = hsrc[o] + gv * v;
        } else {
          int bb = rrow >> 6, ks = rrow & 63, hh = col >> 6, dh = col & 63;
          size_t o;
          if (mode == 2) o = ((((size_t)bb * NH + hh) * KF + ks) * DH + dh);
          else o = ((((size_t)bb * NH + hh) * DH + dh) * KF + ks);
          ((u16*)out)[o] = f2bf(v);
        }
      }
    }
  }
}

// ---------------- fused small-K attention: S=QK^T/8, softmax, O=PV ----------------
__global__ __launch_bounds__(256) void k_attn(const u16* __restrict__ q, const u16* __restrict__ kk,
                                              const u16* __restrict__ vt, u16* __restrict__ o,
                                              float* __restrict__ mattn) {
  __shared__ u16 Qs[128][72];
  __shared__ u16 Ps[128][72];
  __shared__ u16 Ks[64][72];
  __shared__ u16 Vs[64][72];
  int tid = threadIdx.x;
  int t0 = blockIdx.x * 128, hh = blockIdx.y, b = blockIdx.z;
  {
    int row = tid >> 1, seg = tid & 1;
    const uint4* src = (const uint4*)(q + ((size_t)(b * T_ + t0 + row)) * DM + hh * DH + seg * 32);
#pragma unroll
    for (int j = 0; j < 4; ++j) *(uint4*)&Qs[row][seg * 32 + j * 8] = src[j];
  }
  {
    int row = tid >> 2, seg = tid & 3;
    size_t base = (((size_t)b * NH + hh) * 64 + row) * 64 + seg * 16;
    const uint4* sk = (const uint4*)(kk + base);
    const uint4* sv = (const uint4*)(vt + base);
    *(uint4*)&Ks[row][seg * 16] = sk[0];
    *(uint4*)&Ks[row][seg * 16 + 8] = sk[1];
    *(uint4*)&Vs[row][seg * 16] = sv[0];
    *(uint4*)&Vs[row][seg * 16 + 8] = sv[1];
  }
  __syncthreads();
  int l = tid & 63, w = tid >> 6;
  int l15 = l & 15, quad = l >> 4;
  f32x4 zero = {0.f, 0.f, 0.f, 0.f};
  f32x4 sacc[2][4];
#pragma unroll
  for (int mt = 0; mt < 2; ++mt)
#pragma unroll
    for (int nt = 0; nt < 4; ++nt) sacc[mt][nt] = zero;
#pragma unroll
  for (int step = 0; step < 2; ++step) {
    bf16x8 aq0 = *(const bf16x8*)&Qs[w * 32 + l15][step * 32 + quad * 8];
    bf16x8 aq1 = *(const bf16x8*)&Qs[w * 32 + 16 + l15][step * 32 + quad * 8];
#pragma unroll
    for (int nt = 0; nt < 4; ++nt) {
      bf16x8 bk = *(const bf16x8*)&Ks[nt * 16 + l15][step * 32 + quad * 8];
      sacc[0][nt] = __builtin_amdgcn_mfma_f32_16x16x32_bf16(aq0, bk, sacc[0][nt], 0, 0, 0);
      sacc[1][nt] = __builtin_amdgcn_mfma_f32_16x16x32_bf16(aq1, bk, sacc[1][nt], 0, 0, 0);
    }
  }
  float csum[4] = {0, 0, 0, 0};
#pragma unroll
  for (int mt = 0; mt < 2; ++mt) {
#pragma unroll
    for (int reg = 0; reg < 4; ++reg) {
      float s0 = sacc[mt][0][reg] * 0.125f;
      float s1 = sacc[mt][1][reg] * 0.125f;
      float s2 = sacc[mt][2][reg] * 0.125f;
      float s3 = sacc[mt][3][reg] * 0.125f;
      float mx = fmaxf(fmaxf(s0, s1), fmaxf(s2, s3));
#pragma unroll
      for (int off = 1; off < 16; off <<= 1) mx = fmaxf(mx, __shfl_xor(mx, off, 64));
      float p0 = __expf(s0 - mx), p1 = __expf(s1 - mx), p2 = __expf(s2 - mx), p3 = __expf(s3 - mx);
      float sum = p0 + p1 + p2 + p3;
#pragma unroll
      for (int off = 1; off < 16; off <<= 1) sum += __shfl_xor(sum, off, 64);
      float inv = 1.f / sum;
      p0 *= inv; p1 *= inv; p2 *= inv; p3 *= inv;
      int row = w * 32 + mt * 16 + quad * 4 + reg;
      Ps[row][0 * 16 + l15] = f2bf(p0);
      Ps[row][1 * 16 + l15] = f2bf(p1);
      Ps[row][2 * 16 + l15] = f2bf(p2);
      Ps[row][3 * 16 + l15] = f2bf(p3);
      csum[0] += p0; csum[1] += p1; csum[2] += p2; csum[3] += p3;
    }
  }
#pragma unroll
  for (int nt = 0; nt < 4; ++nt) {
    float v = csum[nt];
    v += __shfl_xor(v, 16, 64);
    v += __shfl_xor(v, 32, 64);
    if (quad == 0) atomicAdd(&mattn[b * KF + nt * 16 + l15], v);
  }
  __syncthreads();
  f32x4 oacc[2][4];
#pragma unroll
  for (int mt = 0; mt < 2; ++mt)
#pragma unroll
    for (int nt = 0; nt < 4; ++nt) oacc[mt][nt] = zero;
#pragma unroll
  for (int step = 0; step < 2; ++step) {
    bf16x8 ap0 = *(const bf16x8*)&Ps[w * 32 + l15][step * 32 + quad * 8];
    bf16x8 ap1 = *(const bf16x8*)&Ps[w * 32 + 16 + l15][step * 32 + quad * 8];
#pragma unroll
    for (int nt = 0; nt < 4; ++nt) {
      bf16x8 bv = *(const bf16x8*)&Vs[nt * 16 + l15][step * 32 + quad * 8];
      oacc[0][nt] = __builtin_amdgcn_mfma_f32_16x16x32_bf16(ap0, bv, oacc[0][nt], 0, 0, 0);
      oacc[1][nt] = __builtin_amdgcn_mfma_f32_16x16x32_bf16(ap1, bv, oacc[1][nt], 0, 0, 0);
    }
  }
#pragma unroll
  for (int mt = 0; mt < 2; ++mt)
#pragma unroll
    for (int nt = 0; nt < 4; ++nt)
#pragma unroll
      for (int reg = 0; reg < 4; ++reg) {
        int row = t0 + w * 32 + mt * 16 + quad * 4 + reg;
        int col = hh * DH + nt * 16 + l15;
        o[((size_t)(b * T_ + row)) * DM + col] = f2bf(oacc[mt][nt][reg]);
      }
}

// ---------------- scatter mean attention ----------------
__global__ void k_scatter(const float* __restrict__ mattn, const int* __restrict__ tidx,
                          float* __restrict__ out_attn) {
  int i = threadIdx.x;  // 512 threads
  int b = i >> 6;
  out_attn[(size_t)b * NN + tidx[i]] = mattn[i] * (1.f / 32768.f);
}

extern "C" void kernel_launch(void* const* d_in, const int* in_sizes, int n_in,
                              void* d_out, int out_size, void* d_ws, size_t ws_size,
                              hipStream_t stream) {
  const float* h = (const float*)d_in[0];
  const float* mem = (const float*)d_in[1];
  const float* act = (const float*)d_in[2];
  const float* lng = (const float*)d_in[3];
  const float* lnb = (const float*)d_in[4];
  const float* fw = (const float*)d_in[5];
  const float* fb = (const float*)d_in[6];
  const float* qw = (const float*)d_in[7];
  const float* qb = (const float*)d_in[8];
  const float* kw = (const float*)d_in[9];
  const float* kb = (const float*)d_in[10];
  const float* vw = (const float*)d_in[11];
  const float* vb = (const float*)d_in[12];
  const float* ow = (const float*)d_in[13];
  const float* ob = (const float*)d_in[14];
  const float* awp = (const float*)d_in[15];
  const float* glp = (const float*)d_in[16];
  float* out_h = (float*)d_out;
  float* out_attn = out_h + (size_t)B_ * T_ * DM;

  char* p = (char*)d_ws;
  size_t off = 0;
  auto take = [&](size_t bytes) {
    void* r = p + off;
    off += (bytes + 255) & ~(size_t)255;
    return r;
  };
  u16* hnorm = (u16*)take((size_t)B_ * T_ * DM * 2);  // reused as O after GEMM1
  u16* q_ws = (u16*)take((size_t)B_ * T_ * DM * 2);
  u16* qwT = (u16*)take((size_t)DM * DM * 2);
  u16* kwT = (u16*)take((size_t)DM * DM * 2);
  u16* vwT = (u16*)take((size_t)DM * DM * 2);
  u16* owT = (u16*)take((size_t)DM * DM * 2);
  float* selw = (float*)take((size_t)B_ * NN * 4);
  u16* tmem = (u16*)take((size_t)B_ * KF * DM * 2);
  u16* k_ws = (u16*)take((size_t)B_ * NH * KF * DH * 2);
  u16* vT_ws = (u16*)take((size_t)B_ * NH * KF * DH * 2);
  float* murstd = (float*)take((size_t)B_ * T_ * 2 * 4);
  float* colsum = (float*)take((size_t)B_ * DM * 4);
  float* fq = (float*)take((size_t)B_ * DM * 4);
  float* mattn = (float*)take((size_t)B_ * KF * 4);
  int* tidx = (int*)take((size_t)B_ * KF * 4);
  u16* o_ws = hnorm;

  k_zero<<<1024, 256, 0, stream>>>(out_attn, colsum, mattn);
  k_transpose<<<dim3(32, 32, 4), 256, 0, stream>>>(qw, kw, vw, ow, qwT, kwT, vwT, owT);
  k_ln<<<B_ * T_, 256, 0, stream>>>(h, lng, lnb, hnorm, murstd);
  k_gemm<<<dim3(128, 8), 256, 0, stream>>>(hnorm, qwT, qb, q_ws, nullptr, nullptr, B_ * T_, DM, DM, 0);
  k_summary<<<dim3(4, 16, 8), 256, 0, stream>>>(h, murstd, colsum);
  k_focus<<<32, 256, 0, stream>>>(colsum, lng, lnb, fw, fb, fq);
  k_selection<<<2048, 256, 0, stream>>>(mem, fq, act, awp, selw);
  k_topk<<<8, 1024, 0, stream>>>(selw, tidx);
  k_gather<<<B_ * KF, 256, 0, stream>>>(mem, tidx, tmem);
  k_gemm<<<dim3(4, 8), 256, 0, stream>>>(tmem, kwT, kb, k_ws, nullptr, nullptr, B_ * KF, DM, DM, 2);
  k_gemm<<<dim3(4, 8), 256, 0, stream>>>(tmem, vwT, vb, vT_ws, nullptr, nullptr, B_ * KF, DM, DM, 3);
  k_attn<<<dim3(16, 16, 8), 256, 0, stream>>>(q_ws, k_ws, vT_ws, o_ws, mattn);
  k_gemm<<<dim3(128, 8), 256, 0, stream>>>(o_ws, owT, ob, out_h, h, glp, B_ * T_, DM, DM, 1);
  k_scatter<<<1, 512, 0, stream>>>(mattn, tidx, out_attn);
}

// Round 3
// 627.874 us; speedup vs baseline: 1.2208x; 1.1706x over previous
//
#include <hip/hip_runtime.h>

typedef unsigned short u16;
typedef unsigned int u32;
typedef __bf16 bf16x8 __attribute__((ext_vector_type(8)));
typedef float f32x4 __attribute__((ext_vector_type(4)));

#define DM 1024
#define B_ 8
#define T_ 2048
#define NN 32768
#define NH 16
#define DH 64
#define KF 64

__device__ __forceinline__ u16 f2bf(float f) {
  u32 x = __float_as_uint(f);
  x = (x + 0x7fffu + ((x >> 16) & 1u)) >> 16;
  return (u16)x;
}
__device__ __forceinline__ u32 mono(float f) {
  u32 x = __float_as_uint(f);
  return (x & 0x80000000u) ? ~x : (x | 0x80000000u);
}
// async global->LDS, 16B per lane; LDS dest is wave-uniform base + lane*16
__device__ __forceinline__ void async16(const void* g, void* s) {
  __builtin_amdgcn_global_load_lds((const __attribute__((address_space(1))) void*)g,
                                   (__attribute__((address_space(3))) void*)s, 16, 0, 0);
}

// ---------------- zero-init accumulators + full_attn region ----------------
__global__ void k_zero(float* __restrict__ fullattn, float* __restrict__ colsum,
                       float* __restrict__ mattn, float* __restrict__ fq) {
  int i = blockIdx.x * 256 + threadIdx.x;   // grid = 1024 blocks -> 262144 exactly
  fullattn[i] = 0.f;
  if (i < B_ * DM) { colsum[i] = 0.f; fq[i] = 0.f; }
  if (i < B_ * KF) mattn[i] = 0.f;
}

// ---------------- transpose 4 weights f32(K x N) -> bf16(N x K) ----------------
__global__ __launch_bounds__(256) void k_transpose(
    const float* __restrict__ w0, const float* __restrict__ w1,
    const float* __restrict__ w2, const float* __restrict__ w3,
    u16* __restrict__ o0, u16* __restrict__ o1, u16* __restrict__ o2, u16* __restrict__ o3) {
  __shared__ float t[32][33];
  const float* w = blockIdx.z == 0 ? w0 : blockIdx.z == 1 ? w1 : blockIdx.z == 2 ? w2 : w3;
  u16* o = blockIdx.z == 0 ? o0 : blockIdx.z == 1 ? o1 : blockIdx.z == 2 ? o2 : o3;
  int tx = threadIdx.x & 31, ty = threadIdx.x >> 5;
  int kb = blockIdx.y * 32, nb = blockIdx.x * 32;
#pragma unroll
  for (int j = 0; j < 32; j += 8) t[ty + j][tx] = w[(size_t)(kb + ty + j) * DM + nb + tx];
  __syncthreads();
#pragma unroll
  for (int j = 0; j < 32; j += 8) o[(size_t)(nb + ty + j) * DM + kb + tx] = f2bf(t[tx][ty + j]);
}

// ---------------- LayerNorm: h f32 -> h_norm bf16 + (mu,rstd) per row ----------------
__global__ __launch_bounds__(256) void k_ln(const float* __restrict__ h, const float* __restrict__ g,
                                            const float* __restrict__ be, u16* __restrict__ hn,
                                            float* __restrict__ murstd) {
  int r = blockIdx.x, tid = threadIdx.x;
  float4 v = *(const float4*)(h + (size_t)r * DM + tid * 4);
  float s = v.x + v.y + v.z + v.w;
  float q = v.x * v.x + v.y * v.y + v.z * v.z + v.w * v.w;
#pragma unroll
  for (int off = 1; off < 64; off <<= 1) {
    s += __shfl_xor(s, off, 64);
    q += __shfl_xor(q, off, 64);
  }
  __shared__ float rs[4], rq[4];
  int w = tid >> 6;
  if ((tid & 63) == 0) { rs[w] = s; rq[w] = q; }
  __syncthreads();
  s = rs[0] + rs[1] + rs[2] + rs[3];
  q = rq[0] + rq[1] + rq[2] + rq[3];
  float mu = s * (1.f / 1024.f);
  float rstd = rsqrtf(q * (1.f / 1024.f) - mu * mu + 1e-5f);
  float4 gg = *(const float4*)(g + tid * 4);
  float4 bb = *(const float4*)(be + tid * 4);
  float n0 = (v.x - mu) * rstd * gg.x + bb.x;
  float n1 = (v.y - mu) * rstd * gg.y + bb.y;
  float n2 = (v.z - mu) * rstd * gg.z + bb.z;
  float n3 = (v.w - mu) * rstd * gg.w + bb.w;
  uint2 o;
  o.x = (u32)f2bf(n0) | ((u32)f2bf(n1) << 16);
  o.y = (u32)f2bf(n2) | ((u32)f2bf(n3) << 16);
  *(uint2*)(hn + (size_t)r * DM + tid * 4) = o;
  if (tid == 0) { murstd[r * 2] = mu; murstd[r * 2 + 1] = rstd; }
}

// ---------------- column sums of (h-mu)*rstd (fp32, for h_summary) ----------------
__global__ __launch_bounds__(256) void k_summary(const float* __restrict__ h,
                                                 const float* __restrict__ murstd,
                                                 float* __restrict__ colsum) {
  int col = blockIdx.x * 256 + threadIdx.x;
  int b = blockIdx.z;
  int tb = blockIdx.y * 128;
  float acc = 0.f;
  for (int t = 0; t < 128; ++t) {
    int r = b * T_ + tb + t;
    float mu = murstd[r * 2], rsd = murstd[r * 2 + 1];
    acc += (h[(size_t)r * DM + col] - mu) * rsd;
  }
  atomicAdd(&colsum[b * DM + col], acc);
}

// ---------------- focus_query = h_summary @ focus_w + focus_b (fp32, split-K) -------
__global__ __launch_bounds__(256) void k_focus(const float* __restrict__ colsum,
                                               const float* __restrict__ lng, const float* __restrict__ lnb,
                                               const float* __restrict__ fw, const float* __restrict__ fb,
                                               float* __restrict__ fq) {
  int dout = blockIdx.x * 256 + threadIdx.x;  // 4 x-blocks
  int slice = blockIdx.y;                     // 8 k-slices of 128
  int b = blockIdx.z;                         // 8 batches
  float acc = (slice == 0) ? fb[dout] : 0.f;
  int i0 = slice * 128;
  for (int i = i0; i < i0 + 128; ++i) {
    float hs = lng[i] * (colsum[b * DM + i] * (1.f / 2048.f)) + lnb[i];
    acc += hs * fw[(size_t)i * DM + dout];
  }
  atomicAdd(&fq[b * DM + dout], acc);
}

// ---------------- selection[b][n] = fq[b]·memory[n] + aw*act[b][n] (fp32) ----------------
__global__ __launch_bounds__(256) void k_selection(const float* __restrict__ mem,
                                                   const float* __restrict__ fqg,
                                                   const float* __restrict__ act,
                                                   const float* __restrict__ awp,
                                                   float* __restrict__ sel) {
  __shared__ float fqs[8][1024];
  int tid = threadIdx.x;
#pragma unroll
  for (int i = 0; i < 8; ++i) {
    int e = i * 256 + tid;
    ((float4*)&fqs[0][0])[e] = ((const float4*)fqg)[e];
  }
  __syncthreads();
  float aw = awp[0];
  int l = tid & 63, w = tid >> 6;
  for (int n = blockIdx.x * 4 + w; n < NN; n += gridDim.x * 4) {
    const float* mrow = mem + (size_t)n * DM;
    float accb[8] = {0, 0, 0, 0, 0, 0, 0, 0};
#pragma unroll
    for (int c = 0; c < 4; ++c) {
      int d = c * 256 + l * 4;
      float4 mv = *(const float4*)(mrow + d);
#pragma unroll
      for (int b2 = 0; b2 < 8; ++b2) {
        float4 fv = *(const float4*)&fqs[b2][d];
        accb[b2] += mv.x * fv.x + mv.y * fv.y + mv.z * fv.z + mv.w * fv.w;
      }
    }
#pragma unroll
    for (int off = 1; off < 64; off <<= 1) {
#pragma unroll
      for (int b2 = 0; b2 < 8; ++b2) accb[b2] += __shfl_xor(accb[b2], off, 64);
    }
    if (l < 8) {
      float vsel = accb[0];
#pragma unroll
      for (int j = 1; j < 8; ++j) vsel = (l == j) ? accb[j] : vsel;
      sel[(size_t)l * NN + n] = vsel + aw * act[(size_t)l * NN + n];
    }
  }
}

// ---------------- exact top-64 per batch via 2-level radix histogram ----------------
#define CAND 1024
__global__ __launch_bounds__(1024) void k_topk(const float* __restrict__ sel, int* __restrict__ idx) {
  int b = blockIdx.x, tid = threadIdx.x;
  __shared__ u32 hist[256], hist2[256];
  __shared__ int scb, sA, ssb, sA2, nDef, nCand;
  __shared__ u32 cu[CAND];
  __shared__ int cn[CAND];
  __shared__ unsigned long long amax;
  if (tid < 256) { hist[tid] = 0; hist2[tid] = 0; }
  if (tid == 0) { nDef = 0; nCand = 0; }
  __syncthreads();
  const float* row = sel + (size_t)b * NN;
  for (int i = tid; i < NN; i += 1024) atomicAdd(&hist[mono(row[i]) >> 24], 1u);
  __syncthreads();
  if (tid < 256) {
    u32 s = 0;
    for (int j = tid + 1; j < 256; ++j) s += hist[j];
    if ((int)s < KF && (int)(s + hist[tid]) >= KF) { scb = tid; sA = (int)s; }
  }
  __syncthreads();
  int cb = scb;
  int R = KF - sA;
  for (int i = tid; i < NN; i += 1024) {
    u32 u = mono(row[i]);
    if ((int)(u >> 24) == cb) atomicAdd(&hist2[(u >> 16) & 255], 1u);
  }
  __syncthreads();
  if (tid < 256) {
    u32 s = 0;
    for (int j = tid + 1; j < 256; ++j) s += hist2[j];
    if ((int)s < R && (int)(s + hist2[tid]) >= R) { ssb = tid; sA2 = (int)s; }
  }
  __syncthreads();
  int R2 = R - sA2;
  u32 T16 = ((u32)cb << 8) | (u32)ssb;
  for (int i = tid; i < NN; i += 1024) {
    u32 u = mono(row[i]);
    u32 t = u >> 16;
    if (t > T16) {
      int p = atomicAdd(&nDef, 1);
      idx[b * KF + p] = i;
    } else if (t == T16) {
      int p = atomicAdd(&nCand, 1);
      if (p < CAND) { cu[p] = u; cn[p] = i; }
    }
  }
  __syncthreads();
  int base = nDef;
  int nc = nCand < CAND ? nCand : CAND;
  for (int r = 0; r < R2; ++r) {
    if (tid == 0) amax = 0;
    __syncthreads();
    unsigned long long loc = 0;
    for (int i = tid; i < nc; i += 1024) {
      unsigned long long key = ((unsigned long long)cu[i] << 32) | (u32)i;
      if (key > loc) loc = key;
    }
    if (loc) atomicMax(&amax, loc);
    __syncthreads();
    if (tid == 0) {
      int pos = (int)(amax & 0xffffffffu);
      idx[b * KF + base + r] = cn[pos];
      cu[pos] = 0;
    }
    __syncthreads();
  }
}

// ---------------- gather topk memory rows -> bf16 ----------------
__global__ __launch_bounds__(256) void k_gather(const float* __restrict__ mem,
                                                const int* __restrict__ idx, u16* __restrict__ tm) {
  int rowi = blockIdx.x;
  int n = idx[rowi];
  float4 v = ((const float4*)(mem + (size_t)n * DM))[threadIdx.x];
  uint2 o;
  o.x = (u32)f2bf(v.x) | ((u32)f2bf(v.y) << 16);
  o.y = (u32)f2bf(v.z) | ((u32)f2bf(v.w) << 16);
  *(uint2*)(tm + (size_t)rowi * DM + threadIdx.x * 4) = o;
}

// ---------------- bf16 MFMA GEMM: C = A(MxK) * Bt(NxK)^T + bias ----------------------
// grid x = m-tiles (A-tile-sharing blocks land on same XCD), y = n-tiles,
// z selects weight-set (fused K/V projections).
// Double-buffered LDS, ONE barrier/iter, prefetch issued right after the barrier.
// K-segment rotation swizzle (rot = (row>>1)&3) -> 2-way (free) LDS reads while
// keeping global_load_lds's fixed lane*16B placement.
// mode 0: out bf16 row-major     mode 1: out f32 = h + gate*(acc+bias)
// mode 2: bf16 [b][h][ks][dh]    mode 3: bf16 [b][h][dh][ks]
__global__ __launch_bounds__(256) void k_gemm(const u16* __restrict__ A,
    const u16* __restrict__ Bt0, const float* __restrict__ bias0, void* __restrict__ out0, int mode0,
    const u16* __restrict__ Bt1, const float* __restrict__ bias1, void* __restrict__ out1, int mode1,
    const float* __restrict__ hsrc, const float* __restrict__ gatep, int M, int N, int K) {
  __shared__ __align__(16) u16 As[2][128 * 32];
  __shared__ __align__(16) u16 Bs[2][128 * 32];
  const u16* Bt = blockIdx.z == 0 ? Bt0 : Bt1;
  const float* bias = blockIdx.z == 0 ? bias0 : bias1;
  void* out = blockIdx.z == 0 ? out0 : out1;
  int mode = blockIdx.z == 0 ? mode0 : mode1;
  int tid = threadIdx.x;
  int l = tid & 63, w = tid >> 6;
  int l15 = l & 15, quad = l >> 4;
  int wm = w >> 1, wn = w & 1;
  int m0 = blockIdx.x * 128, n0 = blockIdx.y * 128;
  // staging: lane l -> row w*16+(l>>2), physical seg l&3 holds logical seg q
  int r16 = l >> 2;
  int rot = (r16 >> 1) & 3;
  int q = ((l & 3) - rot) & 3;
  int srow = w * 16 + r16;
  const u16* ga = A + (size_t)(m0 + srow) * K + q * 8;
  const u16* gb = Bt + (size_t)(n0 + srow) * K + q * 8;
  size_t rstride = (size_t)64 * K;
  u16* lA0 = &As[0][(w * 16) * 32];
  u16* lA1 = &As[0][(64 + w * 16) * 32];
  u16* lB0 = &Bs[0][(w * 16) * 32];
  u16* lB1 = &Bs[0][(64 + w * 16) * 32];
  // fragment LDS offsets (u16 units) — iteration-invariant
  int aoff[4], boff[4];
#pragma unroll
  for (int t = 0; t < 4; ++t) {
    int ra = wm * 64 + t * 16 + l15;
    aoff[t] = ra * 32 + (((quad + ((ra >> 1) & 3)) & 3) << 3);
    int rb = wn * 64 + t * 16 + l15;
    boff[t] = rb * 32 + (((quad + ((rb >> 1) & 3)) & 3) << 3);
  }
  f32x4 zero = {0.f, 0.f, 0.f, 0.f};
  f32x4 acc[4][4];
#pragma unroll
  for (int mt = 0; mt < 4; ++mt)
#pragma unroll
    for (int nt = 0; nt < 4; ++nt) acc[mt][nt] = zero;
  const int iters = K >> 5;
  // prologue: prefetch kt=0 into buffer 0
  async16(ga, lA0);
  async16(ga + rstride, lA1);
  async16(gb, lB0);
  async16(gb + rstride, lB1);
  for (int it = 0; it < iters; ++it) {
    int cur = it & 1;
    __syncthreads();  // drains vmcnt: buf[cur] published; buf[cur^1] reads finished
    if (it + 1 < iters) {
      int kt = (it + 1) << 5;
      int bo = (cur ^ 1) * 4096;
      async16(ga + kt, lA0 + bo);
      async16(ga + rstride + kt, lA1 + bo);
      async16(gb + kt, lB0 + bo);
      async16(gb + rstride + kt, lB1 + bo);
    }
    const u16* Ab = &As[cur][0];
    const u16* Bb = &Bs[cur][0];
    bf16x8 af[4], bfr[4];
#pragma unroll
    for (int t = 0; t < 4; ++t) {
      af[t] = *(const bf16x8*)(Ab + aoff[t]);
      bfr[t] = *(const bf16x8*)(Bb + boff[t]);
    }
#pragma unroll
    for (int mt = 0; mt < 4; ++mt)
#pragma unroll
      for (int nt = 0; nt < 4; ++nt)
        acc[mt][nt] = __builtin_amdgcn_mfma_f32_16x16x32_bf16(af[mt], bfr[nt], acc[mt][nt], 0, 0, 0);
  }
  float gv = 0.f;
  if (mode == 1) gv = 1.f / (1.f + __expf(-gatep[0]));
#pragma unroll
  for (int mt = 0; mt < 4; ++mt) {
#pragma unroll
    for (int nt = 0; nt < 4; ++nt) {
      int col = n0 + wn * 64 + nt * 16 + l15;
      float bv = bias[col];
#pragma unroll
      for (int reg = 0; reg < 4; ++reg) {
        int rrow = m0 + wm * 64 + mt * 16 + quad * 4 + reg;
        float v = acc[mt][nt][reg] + bv;
        if (mode == 0) {
          ((u16*)out)[(size_t)rrow * N + col] = f2bf(v);
        } else if (mode == 1) {
          size_t o = (size_t)rrow * N + col;
          ((float*)out)[o] = hsrc[o] + gv * v;
        } else {
          int bb = rrow >> 6, ks = rrow & 63, hh = col >> 6, dh = col & 63;
          size_t o;
          if (mode == 2) o = ((((size_t)bb * NH + hh) * KF + ks) * DH + dh);
          else o = ((((size_t)bb * NH + hh) * DH + dh) * KF + ks);
          ((u16*)out)[o] = f2bf(v);
        }
      }
    }
  }
}

// ---------------- fused small-K attention: S=QK^T/8, softmax, O=PV ----------------
__global__ __launch_bounds__(256) void k_attn(const u16* __restrict__ q, const u16* __restrict__ kk,
                                              const u16* __restrict__ vt, u16* __restrict__ o,
                                              float* __restrict__ mattn) {
  __shared__ u16 Qs[128][72];
  __shared__ u16 Ps[128][72];
  __shared__ u16 Ks[64][72];
  __shared__ u16 Vs[64][72];
  int tid = threadIdx.x;
  int t0 = blockIdx.x * 128, hh = blockIdx.y, b = blockIdx.z;
  {
    int row = tid >> 1, seg = tid & 1;
    const uint4* src = (const uint4*)(q + ((size_t)(b * T_ + t0 + row)) * DM + hh * DH + seg * 32);
#pragma unroll
    for (int j = 0; j < 4; ++j) *(uint4*)&Qs[row][seg * 32 + j * 8] = src[j];
  }
  {
    int row = tid >> 2, seg = tid & 3;
    size_t base = (((size_t)b * NH + hh) * 64 + row) * 64 + seg * 16;
    const uint4* sk = (const uint4*)(kk + base);
    const uint4* sv = (const uint4*)(vt + base);
    *(uint4*)&Ks[row][seg * 16] = sk[0];
    *(uint4*)&Ks[row][seg * 16 + 8] = sk[1];
    *(uint4*)&Vs[row][seg * 16] = sv[0];
    *(uint4*)&Vs[row][seg * 16 + 8] = sv[1];
  }
  __syncthreads();
  int l = tid & 63, w = tid >> 6;
  int l15 = l & 15, quad = l >> 4;
  f32x4 zero = {0.f, 0.f, 0.f, 0.f};
  f32x4 sacc[2][4];
#pragma unroll
  for (int mt = 0; mt < 2; ++mt)
#pragma unroll
    for (int nt = 0; nt < 4; ++nt) sacc[mt][nt] = zero;
#pragma unroll
  for (int step = 0; step < 2; ++step) {
    bf16x8 aq0 = *(const bf16x8*)&Qs[w * 32 + l15][step * 32 + quad * 8];
    bf16x8 aq1 = *(const bf16x8*)&Qs[w * 32 + 16 + l15][step * 32 + quad * 8];
#pragma unroll
    for (int nt = 0; nt < 4; ++nt) {
      bf16x8 bk = *(const bf16x8*)&Ks[nt * 16 + l15][step * 32 + quad * 8];
      sacc[0][nt] = __builtin_amdgcn_mfma_f32_16x16x32_bf16(aq0, bk, sacc[0][nt], 0, 0, 0);
      sacc[1][nt] = __builtin_amdgcn_mfma_f32_16x16x32_bf16(aq1, bk, sacc[1][nt], 0, 0, 0);
    }
  }
  float csum[4] = {0, 0, 0, 0};
#pragma unroll
  for (int mt = 0; mt < 2; ++mt) {
#pragma unroll
    for (int reg = 0; reg < 4; ++reg) {
      float s0 = sacc[mt][0][reg] * 0.125f;
      float s1 = sacc[mt][1][reg] * 0.125f;
      float s2 = sacc[mt][2][reg] * 0.125f;
      float s3 = sacc[mt][3][reg] * 0.125f;
      float mx = fmaxf(fmaxf(s0, s1), fmaxf(s2, s3));
#pragma unroll
      for (int off = 1; off < 16; off <<= 1) mx = fmaxf(mx, __shfl_xor(mx, off, 64));
      float p0 = __expf(s0 - mx), p1 = __expf(s1 - mx), p2 = __expf(s2 - mx), p3 = __expf(s3 - mx);
      float sum = p0 + p1 + p2 + p3;
#pragma unroll
      for (int off = 1; off < 16; off <<= 1) sum += __shfl_xor(sum, off, 64);
      float inv = 1.f / sum;
      p0 *= inv; p1 *= inv; p2 *= inv; p3 *= inv;
      int row = w * 32 + mt * 16 + quad * 4 + reg;
      Ps[row][0 * 16 + l15] = f2bf(p0);
      Ps[row][1 * 16 + l15] = f2bf(p1);
      Ps[row][2 * 16 + l15] = f2bf(p2);
      Ps[row][3 * 16 + l15] = f2bf(p3);
      csum[0] += p0; csum[1] += p1; csum[2] += p2; csum[3] += p3;
    }
  }
#pragma unroll
  for (int nt = 0; nt < 4; ++nt) {
    float v = csum[nt];
    v += __shfl_xor(v, 16, 64);
    v += __shfl_xor(v, 32, 64);
    if (quad == 0) atomicAdd(&mattn[b * KF + nt * 16 + l15], v);
  }
  __syncthreads();
  f32x4 oacc[2][4];
#pragma unroll
  for (int mt = 0; mt < 2; ++mt)
#pragma unroll
    for (int nt = 0; nt < 4; ++nt) oacc[mt][nt] = zero;
#pragma unroll
  for (int step = 0; step < 2; ++step) {
    bf16x8 ap0 = *(const bf16x8*)&Ps[w * 32 + l15][step * 32 + quad * 8];
    bf16x8 ap1 = *(const bf16x8*)&Ps[w * 32 + 16 + l15][step * 32 + quad * 8];
#pragma unroll
    for (int nt = 0; nt < 4; ++nt) {
      bf16x8 bv = *(const bf16x8*)&Vs[nt * 16 + l15][step * 32 + quad * 8];
      oacc[0][nt] = __builtin_amdgcn_mfma_f32_16x16x32_bf16(ap0, bv, oacc[0][nt], 0, 0, 0);
      oacc[1][nt] = __builtin_amdgcn_mfma_f32_16x16x32_bf16(ap1, bv, oacc[1][nt], 0, 0, 0);
    }
  }
#pragma unroll
  for (int mt = 0; mt < 2; ++mt)
#pragma unroll
    for (int nt = 0; nt < 4; ++nt)
#pragma unroll
      for (int reg = 0; reg < 4; ++reg) {
        int row = t0 + w * 32 + mt * 16 + quad * 4 + reg;
        int col = hh * DH + nt * 16 + l15;
        o[((size_t)(b * T_ + row)) * DM + col] = f2bf(oacc[mt][nt][reg]);
      }
}

// ---------------- scatter mean attention ----------------
__global__ void k_scatter(const float* __restrict__ mattn, const int* __restrict__ tidx,
                          float* __restrict__ out_attn) {
  int i = threadIdx.x;  // 512 threads
  int b = i >> 6;
  out_attn[(size_t)b * NN + tidx[i]] = mattn[i] * (1.f / 32768.f);
}

extern "C" void kernel_launch(void* const* d_in, const int* in_sizes, int n_in,
                              void* d_out, int out_size, void* d_ws, size_t ws_size,
                              hipStream_t stream) {
  const float* h = (const float*)d_in[0];
  const float* mem = (const float*)d_in[1];
  const float* act = (const float*)d_in[2];
  const float* lng = (const float*)d_in[3];
  const float* lnb = (const float*)d_in[4];
  const float* fw = (const float*)d_in[5];
  const float* fb = (const float*)d_in[6];
  const float* qw = (const float*)d_in[7];
  const float* qb = (const float*)d_in[8];
  const float* kw = (const float*)d_in[9];
  const float* kb = (const float*)d_in[10];
  const float* vw = (const float*)d_in[11];
  const float* vb = (const float*)d_in[12];
  const float* ow = (const float*)d_in[13];
  const float* ob = (const float*)d_in[14];
  const float* awp = (const float*)d_in[15];
  const float* glp = (const float*)d_in[16];
  float* out_h = (float*)d_out;
  float* out_attn = out_h + (size_t)B_ * T_ * DM;

  char* p = (char*)d_ws;
  size_t off = 0;
  auto take = [&](size_t bytes) {
    void* r = p + off;
    off += (bytes + 255) & ~(size_t)255;
    return r;
  };
  u16* hnorm = (u16*)take((size_t)B_ * T_ * DM * 2);  // reused as O after GEMM1
  u16* q_ws = (u16*)take((size_t)B_ * T_ * DM * 2);
  u16* qwT = (u16*)take((size_t)DM * DM * 2);
  u16* kwT = (u16*)take((size_t)DM * DM * 2);
  u16* vwT = (u16*)take((size_t)DM * DM * 2);
  u16* owT = (u16*)take((size_t)DM * DM * 2);
  float* selw = (float*)take((size_t)B_ * NN * 4);
  u16* tmem = (u16*)take((size_t)B_ * KF * DM * 2);
  u16* k_ws = (u16*)take((size_t)B_ * NH * KF * DH * 2);
  u16* vT_ws = (u16*)take((size_t)B_ * NH * KF * DH * 2);
  float* murstd = (float*)take((size_t)B_ * T_ * 2 * 4);
  float* colsum = (float*)take((size_t)B_ * DM * 4);
  float* fq = (float*)take((size_t)B_ * DM * 4);
  float* mattn = (float*)take((size_t)B_ * KF * 4);
  int* tidx = (int*)take((size_t)B_ * KF * 4);
  u16* o_ws = hnorm;

  k_zero<<<1024, 256, 0, stream>>>(out_attn, colsum, mattn, fq);
  k_transpose<<<dim3(32, 32, 4), 256, 0, stream>>>(qw, kw, vw, ow, qwT, kwT, vwT, owT);
  k_ln<<<B_ * T_, 256, 0, stream>>>(h, lng, lnb, hnorm, murstd);
  k_gemm<<<dim3(128, 8, 1), 256, 0, stream>>>(hnorm, qwT, qb, q_ws, 0,
                                              nullptr, nullptr, nullptr, 0,
                                              nullptr, nullptr, B_ * T_, DM, DM);
  k_summary<<<dim3(4, 16, 8), 256, 0, stream>>>(h, murstd, colsum);
  k_focus<<<dim3(4, 8, 8), 256, 0, stream>>>(colsum, lng, lnb, fw, fb, fq);
  k_selection<<<2048, 256, 0, stream>>>(mem, fq, act, awp, selw);
  k_topk<<<8, 1024, 0, stream>>>(selw, tidx);
  k_gather<<<B_ * KF, 256, 0, stream>>>(mem, tidx, tmem);
  k_gemm<<<dim3(4, 8, 2), 256, 0, stream>>>(tmem, kwT, kb, k_ws, 2,
                                            vwT, vb, vT_ws, 3,
                                            nullptr, nullptr, B_ * KF, DM, DM);
  k_attn<<<dim3(16, 16, 8), 256, 0, stream>>>(q_ws, k_ws, vT_ws, o_ws, mattn);
  k_gemm<<<dim3(128, 8, 1), 256, 0, stream>>>(o_ws, owT, ob, out_h, 1,
                                              nullptr, nullptr, nullptr, 0,
                                              h, glp, B_ * T_, DM, DM);
  k_scatter<<<1, 512, 0, stream>>>(mattn, tidx, out_attn);
}